// Round 2
// baseline (29154.330 us; speedup 1.0000x reference)
//
#include <hip/hip_runtime.h>

#define BB   512
#define SS   256
#define NIN  128
#define DH   1024
#define DC   1152   // NIN + DH
#define NOUT 128
#define EPSV 1e-5f
#define NWG  256
#define NTHR 512

typedef _Float16 f16;
typedef _Float16 f16x8 __attribute__((ext_vector_type(8)));
typedef _Float16 f16x4 __attribute__((ext_vector_type(4)));
typedef float    f32x4 __attribute__((ext_vector_type(4)));

__device__ __forceinline__ float sigmoid_(float x) { return 1.0f / (1.0f + __expf(-x)); }
__device__ __forceinline__ float tanh_(float x) {
    x = fminf(fmaxf(x, -15.0f), 15.0f);
    float e = __expf(2.0f * x);
    return (e - 1.0f) / (e + 1.0f);
}

// ---------------- software grid barrier (monotonic counter, no reset races) ----------------
__device__ __forceinline__ void gbar(unsigned* cnt, unsigned* gen, unsigned idx) {
    __syncthreads();
    if (threadIdx.x == 0) {
        __threadfence();  // device-scope release of this WG's writes
        unsigned n = __hip_atomic_fetch_add(cnt, 1u, __ATOMIC_ACQ_REL, __HIP_MEMORY_SCOPE_AGENT) + 1u;
        const unsigned tgt = (idx + 1u) * NWG;
        if (n == tgt) {
            __hip_atomic_store(gen, idx + 1u, __ATOMIC_RELEASE, __HIP_MEMORY_SCOPE_AGENT);
        } else {
            while (__hip_atomic_load(gen, __ATOMIC_ACQUIRE, __HIP_MEMORY_SCOPE_AGENT) < idx + 1u)
                __builtin_amdgcn_s_sleep(1);
        }
        __threadfence();  // device-scope acquire before reading others' writes
    }
    __syncthreads();
}

// ---------------- weight conversion (fp32 -> fp16), once per launch ----------------
__global__ void k_convert(const float* __restrict__ Wu, const float* __restrict__ Wr,
                          const float* __restrict__ Wh_, const float* __restrict__ Wo_,
                          f16* __restrict__ wur, f16* __restrict__ wh, f16* __restrict__ wo)
{
    const int stride = gridDim.x * blockDim.x;
    const int i0 = blockIdx.x * blockDim.x + threadIdx.x;
    for (int i = i0; i < 2048 * 1152 / 4; i += stride) {
        int base = i * 4;
        int n = base / 1152, k = base % 1152;
        const float* src = (n < 1024) ? (Wu + (size_t)n * 1152 + k) : (Wr + (size_t)(n - 1024) * 1152 + k);
        float4 v = *(const float4*)src;
        f16x4 o; o[0] = (f16)v.x; o[1] = (f16)v.y; o[2] = (f16)v.z; o[3] = (f16)v.w;
        *(f16x4*)(wur + base) = o;
    }
    for (int i = i0; i < 1024 * 1152 / 4; i += stride) {
        int base = i * 4;
        float4 v = *(const float4*)(Wh_ + base);
        f16x4 o; o[0] = (f16)v.x; o[1] = (f16)v.y; o[2] = (f16)v.z; o[3] = (f16)v.w;
        *(f16x4*)(wh + base) = o;
    }
    for (int i = i0; i < 128 * 1024 / 4; i += stride) {
        int base = i * 4;
        float4 v = *(const float4*)(Wo_ + base);
        f16x4 o; o[0] = (f16)v.x; o[1] = (f16)v.y; o[2] = (f16)v.z; o[3] = (f16)v.w;
        *(f16x4*)(wo + base) = o;
    }
}

// ---------------- init: comb = [x_0, 0], h32 = 0, stats = 0, barrier state = 0 ----------------
__global__ void k_init(const float* __restrict__ X, f16* __restrict__ comb, float* __restrict__ h32,
                       float* __restrict__ ssum_ur, float* __restrict__ ssq_ur,
                       float* __restrict__ ssum_c, float* __restrict__ ssq_c,
                       unsigned* __restrict__ cnt, unsigned* __restrict__ gen)
{
    const int stride = gridDim.x * blockDim.x;
    const int i0 = blockIdx.x * blockDim.x + threadIdx.x;
    for (int i = i0; i < BB * DC / 4; i += stride) {
        int base = i * 4;
        int m = base / DC, k = base % DC;
        f16x4 o;
        if (k < NIN) {
            float4 v = *(const float4*)(X + (size_t)m * SS * NIN + k);  // s = 0
            o[0] = (f16)v.x; o[1] = (f16)v.y; o[2] = (f16)v.z; o[3] = (f16)v.w;
        } else {
            o[0] = (f16)0.f; o[1] = (f16)0.f; o[2] = (f16)0.f; o[3] = (f16)0.f;
        }
        *(f16x4*)(comb + base) = o;
    }
    for (int i = i0; i < BB * DH / 4; i += stride)
        *(float4*)(h32 + i * 4) = make_float4(0.f, 0.f, 0.f, 0.f);
    for (int i = i0; i < 2 * 2048; i += stride) { ssum_ur[i] = 0.f; ssq_ur[i] = 0.f; }
    for (int i = i0; i < 2 * 1024; i += stride) { ssum_c[i] = 0.f; ssq_c[i] = 0.f; }
    if (i0 == 0) { *cnt = 0u; *gen = 0u; }
}

// ---------------- 64x64 GEMM job, 8 waves: 2x2 spatial (32x32 each) x 2-way K-split ----------------
// C[64,64] = A[m0:64, K] * B[n0:64, K]^T ; smem = f16[2][2][64][72] (As=smem[0], Bs=smem[1])
template<int KT, bool OEPI>
__device__ __forceinline__ void gemm_job(
    const f16* __restrict__ A, int lda, const f16* __restrict__ Bm,
    float* __restrict__ C, int ldc,
    float* __restrict__ ssum, float* __restrict__ ssq,
    const float* __restrict__ bo, float* __restrict__ outp, int so,
    int m0, int n0, f16 (*As)[64][72], f16 (*Bs)[64][72])
{
    constexpr int KH = KT / 2;
    constexpr int NC = KH / 64;
    const int tid  = threadIdx.x;
    const int lane = tid & 63;
    const int wave = tid >> 6;
    const int g    = tid >> 8;           // K-half group (waves 0-3 -> 0, 4-7 -> 1)
    const int sq   = wave & 3, wm = sq >> 1, wn = sq & 1;
    const int t    = tid & 255;
    const int r0   = t >> 3, kg = t & 7;

    const f16* Ap  = A  + (size_t)(m0 + r0) * lda + g * KH + kg * 8;
    const f16* Ap2 = Ap + (size_t)32 * lda;
    const f16* Bp  = Bm + (size_t)(n0 + r0) * KT + g * KH + kg * 8;
    const f16* Bp2 = Bp + (size_t)32 * KT;

    f32x4 acc[2][2] = {};
    f16x8 pa0 = *(const f16x8*)Ap;
    f16x8 pa1 = *(const f16x8*)Ap2;
    f16x8 pb0 = *(const f16x8*)Bp;
    f16x8 pb1 = *(const f16x8*)Bp2;

    for (int c = 0; c < NC; ++c) {
        *(f16x8*)&As[g][r0][kg * 8]      = pa0;
        *(f16x8*)&As[g][r0 + 32][kg * 8] = pa1;
        *(f16x8*)&Bs[g][r0][kg * 8]      = pb0;
        *(f16x8*)&Bs[g][r0 + 32][kg * 8] = pb1;
        __syncthreads();
        if (c + 1 < NC) {
            pa0 = *(const f16x8*)(Ap  + (c + 1) * 64);
            pa1 = *(const f16x8*)(Ap2 + (c + 1) * 64);
            pb0 = *(const f16x8*)(Bp  + (c + 1) * 64);
            pb1 = *(const f16x8*)(Bp2 + (c + 1) * 64);
        }
#pragma unroll
        for (int ks = 0; ks < 2; ++ks) {
            const int kofs = ks * 32 + (lane >> 4) * 8;
            f16x8 a0 = *(const f16x8*)&As[g][wm * 32 + (lane & 15)][kofs];
            f16x8 a1 = *(const f16x8*)&As[g][wm * 32 + 16 + (lane & 15)][kofs];
            f16x8 b0 = *(const f16x8*)&Bs[g][wn * 32 + (lane & 15)][kofs];
            f16x8 b1 = *(const f16x8*)&Bs[g][wn * 32 + 16 + (lane & 15)][kofs];
            acc[0][0] = __builtin_amdgcn_mfma_f32_16x16x32_f16(a0, b0, acc[0][0], 0, 0, 0);
            acc[0][1] = __builtin_amdgcn_mfma_f32_16x16x32_f16(a0, b1, acc[0][1], 0, 0, 0);
            acc[1][0] = __builtin_amdgcn_mfma_f32_16x16x32_f16(a1, b0, acc[1][0], 0, 0, 0);
            acc[1][1] = __builtin_amdgcn_mfma_f32_16x16x32_f16(a1, b1, acc[1][1], 0, 0, 0);
        }
        __syncthreads();
    }

    // K-split reduction through LDS (stride 20 floats: 16B-aligned vec4, once per job)
    float* red = (float*)As;
    const int rbase = (sq * 64 + lane) * 20;
    if (g == 1) {
#pragma unroll
        for (int fm = 0; fm < 2; ++fm)
#pragma unroll
            for (int fn = 0; fn < 2; ++fn)
                *(f32x4*)&red[rbase + (fm * 2 + fn) * 4] = acc[fm][fn];
    }
    __syncthreads();
    if (g == 0) {
#pragma unroll
        for (int fm = 0; fm < 2; ++fm)
#pragma unroll
            for (int fn = 0; fn < 2; ++fn)
                acc[fm][fn] += *(const f32x4*)&red[rbase + (fm * 2 + fn) * 4];

#pragma unroll
        for (int fm = 0; fm < 2; ++fm) {
#pragma unroll
            for (int fn = 0; fn < 2; ++fn) {
                const int row = m0 + wm * 32 + fm * 16 + (lane >> 4) * 4;
                const int col = n0 + wn * 32 + fn * 16 + (lane & 15);
                if constexpr (OEPI) {
#pragma unroll
                    for (int i = 0; i < 4; ++i) {
                        float v = tanh_(acc[fm][fn][i] + bo[col]);
                        outp[(size_t)(row + i) * (SS * NOUT) + (size_t)so * NOUT + col] = v;
                    }
                } else {
#pragma unroll
                    for (int i = 0; i < 4; ++i)
                        C[(size_t)(row + i) * ldc + col] = acc[fm][fn][i];
                }
            }
        }
        if constexpr (!OEPI) {
#pragma unroll
            for (int fn = 0; fn < 2; ++fn) {
                float s1 = 0.f, s2 = 0.f;
#pragma unroll
                for (int fm = 0; fm < 2; ++fm)
#pragma unroll
                    for (int i = 0; i < 4; ++i) { float v = acc[fm][fn][i]; s1 += v; s2 += v * v; }
                s1 += __shfl_xor(s1, 16, 64); s1 += __shfl_xor(s1, 32, 64);
                s2 += __shfl_xor(s2, 16, 64); s2 += __shfl_xor(s2, 32, 64);
                if (lane < 16) {
                    const int col = n0 + wn * 32 + fn * 16 + lane;
                    atomicAdd(&ssum[col], s1);
                    atomicAdd(&ssq[col], s2);
                }
            }
        }
    }
}

// ---------------- one full GRU step: 4 phases, 3 grid barriers ----------------
__global__ __launch_bounds__(NTHR)
void k_step(f16* __restrict__ comb, f16* __restrict__ h16, float* __restrict__ h32,
            const f16* __restrict__ Wur, const f16* __restrict__ Wh16, const f16* __restrict__ Wo16,
            float* __restrict__ pre_ur, float* __restrict__ pre_c,
            float* __restrict__ ssum_ur, float* __restrict__ ssq_ur,
            float* __restrict__ ssum_c, float* __restrict__ ssq_c,
            float* __restrict__ outp, const float* __restrict__ X,
            const float* __restrict__ g_u, const float* __restrict__ be_u,
            const float* __restrict__ g_r, const float* __restrict__ be_r,
            const float* __restrict__ g_h, const float* __restrict__ be_h,
            const float* __restrict__ b_o,
            unsigned* __restrict__ cnt, unsigned* __restrict__ gen, int s)
{
    __shared__ __align__(16) f16 smem[2][2][64][72];
    const int wg  = blockIdx.x;
    const int tid = threadIdx.x;
    const int par = s & 1, nxt = 1 - par;
    float* su = ssum_ur + par * 2048; float* qu = ssq_ur + par * 2048;
    float* sc = ssum_c  + par * 1024; float* qc = ssq_c  + par * 1024;

    // ---- phase 1: pre_ur = comb @ Wur^T (+ stats); 256 jobs of 64x64
    {
        const int n0 = (wg & 31) * 64, m0 = (wg >> 5) * 64;
        gemm_job<DC, false>(comb, DC, Wur, pre_ur, 2048, su, qu,
                            nullptr, nullptr, 0, m0, n0, smem[0], smem[1]);
    }
    gbar(cnt, gen, (unsigned)(s * 3 + 0));

    // ---- phase 2: r = sigmoid(BN(pre_r)); comb_h <- fp16(r*h)   (1 float4 per thread)
    {
        const int i = wg * NTHR + tid;
        const int m = i >> 8, j4 = (i & 255) << 2;
        float4 prv = *(const float4*)(pre_ur + (size_t)m * 2048 + 1024 + j4);
        float4 hv  = *(const float4*)(h32 + (size_t)m * 1024 + j4);
        float p[4] = {prv.x, prv.y, prv.z, prv.w};
        float h[4] = {hv.x, hv.y, hv.z, hv.w};
        f16x4 o;
#pragma unroll
        for (int t = 0; t < 4; ++t) {
            const int col = 1024 + j4 + t;
            float mu  = su[col] * (1.0f / 512.0f);
            float var = fmaxf(qu[col] * (1.0f / 512.0f) - mu * mu, 0.f);
            float r   = sigmoid_(g_r[j4 + t] * ((p[t] - mu) * rsqrtf(var + EPSV)) + be_r[j4 + t]);
            o[t] = (f16)(r * h[t]);
        }
        *(f16x4*)(comb + (size_t)m * DC + NIN + j4) = o;
    }
    gbar(cnt, gen, (unsigned)(s * 3 + 1));

    // ---- phase 3: pre_c = comb2 @ Wh^T (+ stats) on WGs 0..127;  o(s-1) GEMM on WGs 128..143
    if (wg < 128) {
        const int n0 = (wg & 15) * 64, m0 = (wg >> 4) * 64;
        gemm_job<DC, false>(comb, DC, Wh16, pre_c, 1024, sc, qc,
                            nullptr, nullptr, 0, m0, n0, smem[0], smem[1]);
    } else if (wg < 144 && s > 0) {
        const int j = wg - 128;
        const int n0 = (j & 1) * 64, m0 = (j >> 1) * 64;
        gemm_job<DH, true>(h16, DH, Wo16, nullptr, 0, nullptr, nullptr,
                           b_o, outp, s - 1, m0, n0, smem[0], smem[1]);
    }
    gbar(cnt, gen, (unsigned)(s * 3 + 2));

    // ---- phase 4: u, c, h_new; write h32/h16/comb_h; prefetch x(s+1); zero next stats
    {
        const int i = wg * NTHR + tid;
        const int m = i >> 8, j4 = (i & 255) << 2;
        float4 puv = *(const float4*)(pre_ur + (size_t)m * 2048 + j4);
        float4 pcv = *(const float4*)(pre_c + (size_t)m * 1024 + j4);
        float4 hv  = *(const float4*)(h32 + (size_t)m * 1024 + j4);
        float pu[4] = {puv.x, puv.y, puv.z, puv.w};
        float pc[4] = {pcv.x, pcv.y, pcv.z, pcv.w};
        float h[4]  = {hv.x, hv.y, hv.z, hv.w};
        float hn[4];
        f16x4 o;
#pragma unroll
        for (int t = 0; t < 4; ++t) {
            const int col = j4 + t;
            float mu_u  = su[col] * (1.0f / 512.0f);
            float var_u = fmaxf(qu[col] * (1.0f / 512.0f) - mu_u * mu_u, 0.f);
            float u = sigmoid_(g_u[col] * ((pu[t] - mu_u) * rsqrtf(var_u + EPSV)) + be_u[col]);
            float mu_c  = sc[col] * (1.0f / 512.0f);
            float var_c = fmaxf(qc[col] * (1.0f / 512.0f) - mu_c * mu_c, 0.f);
            float c = tanh_(g_h[col] * ((pc[t] - mu_c) * rsqrtf(var_c + EPSV)) + be_h[col]);
            float hnew = (1.f - u) * c + u * h[t];
            hn[t] = hnew; o[t] = (f16)hnew;
        }
        *(float4*)(h32 + (size_t)m * 1024 + j4) = make_float4(hn[0], hn[1], hn[2], hn[3]);
        *(f16x4*)(comb + (size_t)m * DC + NIN + j4) = o;
        *(f16x4*)(h16 + (size_t)m * 1024 + j4) = o;
        if (j4 < NIN && s + 1 < SS) {
            float4 xv = *(const float4*)(X + (size_t)m * SS * NIN + (size_t)(s + 1) * NIN + j4);
            f16x4 xo; xo[0] = (f16)xv.x; xo[1] = (f16)xv.y; xo[2] = (f16)xv.z; xo[3] = (f16)xv.w;
            *(f16x4*)(comb + (size_t)m * DC + j4) = xo;
        }
        if (i < 2048) { ssum_ur[nxt * 2048 + i] = 0.f; ssq_ur[nxt * 2048 + i] = 0.f; }
        if (i < 1024) { ssum_c[nxt * 1024 + i] = 0.f; ssq_c[nxt * 1024 + i] = 0.f; }
    }
}

// ---------------- standalone 4-wave GEMM (used once, for the final o at s=255) ----------------
template<int KT, bool STATS, bool OEPI>
__global__ __launch_bounds__(256, 1)
void k_gemm(const f16* __restrict__ A, int lda,
            const f16* __restrict__ Bm,
            float* __restrict__ C, int ldc,
            float* __restrict__ ssum, float* __restrict__ ssq,
            const float* __restrict__ bo, float* __restrict__ outp, int s)
{
    __shared__ f16 As[64][72];
    __shared__ f16 Bs[64][72];
    const int tid  = threadIdx.x;
    const int lane = tid & 63;
    const int w    = tid >> 6, wm = w >> 1, wn = w & 1;
    const int m0   = blockIdx.y * 64, n0 = blockIdx.x * 64;
    const int r0   = tid >> 3;
    const int kg   = tid & 7;

    const f16* Ap = A + (size_t)m0 * lda + kg * 8;
    const f16* Bp = Bm + (size_t)n0 * KT + kg * 8;

    f32x4 acc[2][2] = {};

    f16x8 pa0 = *(const f16x8*)(Ap + (size_t)r0 * lda);
    f16x8 pa1 = *(const f16x8*)(Ap + (size_t)(r0 + 32) * lda);
    f16x8 pb0 = *(const f16x8*)(Bp + (size_t)r0 * KT);
    f16x8 pb1 = *(const f16x8*)(Bp + (size_t)(r0 + 32) * KT);

    for (int kc = 0; kc < KT; kc += 64) {
        *(f16x8*)&As[r0][kg * 8]      = pa0;
        *(f16x8*)&As[r0 + 32][kg * 8] = pa1;
        *(f16x8*)&Bs[r0][kg * 8]      = pb0;
        *(f16x8*)&Bs[r0 + 32][kg * 8] = pb1;
        __syncthreads();
        if (kc + 64 < KT) {
            pa0 = *(const f16x8*)(Ap + (size_t)r0 * lda + kc + 64);
            pa1 = *(const f16x8*)(Ap + (size_t)(r0 + 32) * lda + kc + 64);
            pb0 = *(const f16x8*)(Bp + (size_t)r0 * KT + kc + 64);
            pb1 = *(const f16x8*)(Bp + (size_t)(r0 + 32) * KT + kc + 64);
        }
#pragma unroll
        for (int ks = 0; ks < 2; ++ks) {
            const int kofs = ks * 32 + (lane >> 4) * 8;
            f16x8 a0 = *(const f16x8*)&As[wm * 32 + (lane & 15)][kofs];
            f16x8 a1 = *(const f16x8*)&As[wm * 32 + 16 + (lane & 15)][kofs];
            f16x8 b0 = *(const f16x8*)&Bs[wn * 32 + (lane & 15)][kofs];
            f16x8 b1 = *(const f16x8*)&Bs[wn * 32 + 16 + (lane & 15)][kofs];
            acc[0][0] = __builtin_amdgcn_mfma_f32_16x16x32_f16(a0, b0, acc[0][0], 0, 0, 0);
            acc[0][1] = __builtin_amdgcn_mfma_f32_16x16x32_f16(a0, b1, acc[0][1], 0, 0, 0);
            acc[1][0] = __builtin_amdgcn_mfma_f32_16x16x32_f16(a1, b0, acc[1][0], 0, 0, 0);
            acc[1][1] = __builtin_amdgcn_mfma_f32_16x16x32_f16(a1, b1, acc[1][1], 0, 0, 0);
        }
        __syncthreads();
    }

#pragma unroll
    for (int fm = 0; fm < 2; ++fm) {
#pragma unroll
        for (int fn = 0; fn < 2; ++fn) {
            const int row = m0 + wm * 32 + fm * 16 + (lane >> 4) * 4;
            const int col = n0 + wn * 32 + fn * 16 + (lane & 15);
            if constexpr (OEPI) {
#pragma unroll
                for (int i = 0; i < 4; ++i) {
                    float v = tanh_(acc[fm][fn][i] + bo[col]);
                    outp[(size_t)(row + i) * (SS * NOUT) + (size_t)s * NOUT + col] = v;
                }
            } else {
#pragma unroll
                for (int i = 0; i < 4; ++i)
                    C[(size_t)(row + i) * ldc + col] = acc[fm][fn][i];
            }
        }
    }
}

// ---------------- host launch ----------------
extern "C" void kernel_launch(void* const* d_in, const int* in_sizes, int n_in,
                              void* d_out, int out_size, void* d_ws, size_t ws_size,
                              hipStream_t stream)
{
    const float* X    = (const float*)d_in[0];
    const float* W_u  = (const float*)d_in[1];
    const float* W_r  = (const float*)d_in[3];
    const float* W_h  = (const float*)d_in[5];
    const float* W_o  = (const float*)d_in[7];
    const float* b_o  = (const float*)d_in[8];
    const float* g_u  = (const float*)d_in[9];
    const float* be_u = (const float*)d_in[10];
    const float* g_r  = (const float*)d_in[11];
    const float* be_r = (const float*)d_in[12];
    const float* g_h  = (const float*)d_in[13];
    const float* be_h = (const float*)d_in[14];
    float* out = (float*)d_out;

    char* p = (char*)d_ws;
    auto alloc = [&](size_t bytes) { char* r = p; p += (bytes + 255) & ~(size_t)255; return r; };
    f16*   comb    = (f16*)alloc((size_t)BB * DC * 2);
    f16*   h16     = (f16*)alloc((size_t)BB * DH * 2);
    f16*   Wur     = (f16*)alloc((size_t)2048 * DC * 2);
    f16*   Wh16    = (f16*)alloc((size_t)DH * DC * 2);
    f16*   Wo16    = (f16*)alloc((size_t)NOUT * DH * 2);
    float* pre_ur  = (float*)alloc((size_t)BB * 2048 * 4);
    float* pre_c   = (float*)alloc((size_t)BB * DH * 4);
    float* h32     = (float*)alloc((size_t)BB * DH * 4);
    float* ssum_ur = (float*)alloc(2 * 2048 * 4);
    float* ssq_ur  = (float*)alloc(2 * 2048 * 4);
    float* ssum_c  = (float*)alloc(2 * 1024 * 4);
    float* ssq_c   = (float*)alloc(2 * 1024 * 4);
    unsigned* cnt  = (unsigned*)alloc(256);   // cnt at +0, gen separate line
    unsigned* gen  = (unsigned*)alloc(256);

    k_convert<<<1024, 256, 0, stream>>>(W_u, W_r, W_h, W_o, Wur, Wh16, Wo16);
    k_init<<<1024, 256, 0, stream>>>(X, comb, h32, ssum_ur, ssq_ur, ssum_c, ssq_c, cnt, gen);

    for (int s = 0; s < SS; ++s) {
        k_step<<<NWG, NTHR, 0, stream>>>(comb, h16, h32, Wur, Wh16, Wo16,
                                         pre_ur, pre_c,
                                         ssum_ur, ssq_ur, ssum_c, ssq_c,
                                         out, X,
                                         g_u, be_u, g_r, be_r, g_h, be_h, b_o,
                                         cnt, gen, s);
    }
    // final o for s = 255 (h16 holds h_new(255))
    k_gemm<DH, false, true><<<dim3(2, 8), 256, 0, stream>>>(
        h16, DH, Wo16, nullptr, 0, nullptr, nullptr, b_o, out, 255);
}

// Round 5
// 8055.199 us; speedup vs baseline: 3.6193x; 3.6193x over previous
//
#include <hip/hip_runtime.h>

#define BB   512
#define SS   256
#define NIN  128
#define DH   1024
#define DC   1152   // NIN + DH
#define NOUT 128
#define EPSV 1e-5f

typedef _Float16 f16;
typedef _Float16 f16x8 __attribute__((ext_vector_type(8)));
typedef _Float16 f16x4 __attribute__((ext_vector_type(4)));
typedef float    f32x4 __attribute__((ext_vector_type(4)));

__device__ __forceinline__ float sigmoid_(float x) { return 1.0f / (1.0f + __expf(-x)); }
__device__ __forceinline__ float tanh_(float x) {
    x = fminf(fmaxf(x, -15.0f), 15.0f);
    float e = __expf(2.0f * x);
    return (e - 1.0f) / (e + 1.0f);
}

// ---------------- weight conversion (fp32 -> fp16), once per launch ----------------
__global__ void k_convert(const float* __restrict__ Wu, const float* __restrict__ Wr,
                          const float* __restrict__ Wh_, const float* __restrict__ Wo_,
                          f16* __restrict__ wur, f16* __restrict__ wh, f16* __restrict__ wo)
{
    const int stride = gridDim.x * blockDim.x;
    const int i0 = blockIdx.x * blockDim.x + threadIdx.x;
    for (int i = i0; i < 2048 * 1152 / 4; i += stride) {
        int base = i * 4;
        int n = base / 1152, k = base % 1152;
        const float* src = (n < 1024) ? (Wu + (size_t)n * 1152 + k) : (Wr + (size_t)(n - 1024) * 1152 + k);
        float4 v = *(const float4*)src;
        f16x4 o; o[0] = (f16)v.x; o[1] = (f16)v.y; o[2] = (f16)v.z; o[3] = (f16)v.w;
        *(f16x4*)(wur + base) = o;
    }
    for (int i = i0; i < 1024 * 1152 / 4; i += stride) {
        int base = i * 4;
        float4 v = *(const float4*)(Wh_ + base);
        f16x4 o; o[0] = (f16)v.x; o[1] = (f16)v.y; o[2] = (f16)v.z; o[3] = (f16)v.w;
        *(f16x4*)(wh + base) = o;
    }
    for (int i = i0; i < 128 * 1024 / 4; i += stride) {
        int base = i * 4;
        float4 v = *(const float4*)(Wo_ + base);
        f16x4 o; o[0] = (f16)v.x; o[1] = (f16)v.y; o[2] = (f16)v.z; o[3] = (f16)v.w;
        *(f16x4*)(wo + base) = o;
    }
}

// ---------------- init: comb = [x_0, 0], h32 = 0, stats = 0 ----------------
__global__ void k_init(const float* __restrict__ X, f16* __restrict__ comb, float* __restrict__ h32,
                       float* __restrict__ ssum_ur, float* __restrict__ ssq_ur,
                       float* __restrict__ ssum_c, float* __restrict__ ssq_c)
{
    const int stride = gridDim.x * blockDim.x;
    const int i0 = blockIdx.x * blockDim.x + threadIdx.x;
    for (int i = i0; i < BB * DC / 4; i += stride) {
        int base = i * 4;
        int m = base / DC, k = base % DC;
        f16x4 o;
        if (k < NIN) {
            float4 v = *(const float4*)(X + (size_t)m * SS * NIN + k);  // s = 0
            o[0] = (f16)v.x; o[1] = (f16)v.y; o[2] = (f16)v.z; o[3] = (f16)v.w;
        } else {
            o[0] = (f16)0.f; o[1] = (f16)0.f; o[2] = (f16)0.f; o[3] = (f16)0.f;
        }
        *(f16x4*)(comb + base) = o;
    }
    for (int i = i0; i < BB * DH / 4; i += stride)
        *(float4*)(h32 + i * 4) = make_float4(0.f, 0.f, 0.f, 0.f);
    for (int i = i0; i < 2 * 2048; i += stride) { ssum_ur[i] = 0.f; ssq_ur[i] = 0.f; }
    for (int i = i0; i < 2 * 1024; i += stride) { ssum_c[i] = 0.f; ssq_c[i] = 0.f; }
}

// ---------------- 64x64 GEMM job, 8 waves: 2x2 spatial (32x32) x 2-way K-split ----------------
// verified numerics (rounds 1-2).  C[64,64] = A[m0:64,K] * B[n0:64,K]^T
template<int KT, bool OEPI>
__device__ __forceinline__ void gemm_job(
    const f16* __restrict__ A, int lda, const f16* __restrict__ Bm,
    float* __restrict__ C, int ldc,
    float* __restrict__ ssum, float* __restrict__ ssq,
    const float* __restrict__ bo, float* __restrict__ outp, int so,
    int m0, int n0, f16 (*As)[64][72], f16 (*Bs)[64][72])
{
    constexpr int KH = KT / 2;
    constexpr int NC = KH / 64;
    const int tid  = threadIdx.x;
    const int lane = tid & 63;
    const int wave = tid >> 6;
    const int g    = tid >> 8;           // K-half group
    const int sq   = wave & 3, wm = sq >> 1, wn = sq & 1;
    const int t    = tid & 255;
    const int r0   = t >> 3, kg = t & 7;

    const f16* Ap  = A  + (size_t)(m0 + r0) * lda + g * KH + kg * 8;
    const f16* Ap2 = Ap + (size_t)32 * lda;
    const f16* Bp  = Bm + (size_t)(n0 + r0) * KT + g * KH + kg * 8;
    const f16* Bp2 = Bp + (size_t)32 * KT;

    f32x4 acc[2][2] = {};
    f16x8 pa0 = *(const f16x8*)Ap;
    f16x8 pa1 = *(const f16x8*)Ap2;
    f16x8 pb0 = *(const f16x8*)Bp;
    f16x8 pb1 = *(const f16x8*)Bp2;

    for (int c = 0; c < NC; ++c) {
        *(f16x8*)&As[g][r0][kg * 8]      = pa0;
        *(f16x8*)&As[g][r0 + 32][kg * 8] = pa1;
        *(f16x8*)&Bs[g][r0][kg * 8]      = pb0;
        *(f16x8*)&Bs[g][r0 + 32][kg * 8] = pb1;
        __syncthreads();
        if (c + 1 < NC) {
            pa0 = *(const f16x8*)(Ap  + (c + 1) * 64);
            pa1 = *(const f16x8*)(Ap2 + (c + 1) * 64);
            pb0 = *(const f16x8*)(Bp  + (c + 1) * 64);
            pb1 = *(const f16x8*)(Bp2 + (c + 1) * 64);
        }
#pragma unroll
        for (int ks = 0; ks < 2; ++ks) {
            const int kofs = ks * 32 + (lane >> 4) * 8;
            f16x8 a0 = *(const f16x8*)&As[g][wm * 32 + (lane & 15)][kofs];
            f16x8 a1 = *(const f16x8*)&As[g][wm * 32 + 16 + (lane & 15)][kofs];
            f16x8 b0 = *(const f16x8*)&Bs[g][wn * 32 + (lane & 15)][kofs];
            f16x8 b1 = *(const f16x8*)&Bs[g][wn * 32 + 16 + (lane & 15)][kofs];
            acc[0][0] = __builtin_amdgcn_mfma_f32_16x16x32_f16(a0, b0, acc[0][0], 0, 0, 0);
            acc[0][1] = __builtin_amdgcn_mfma_f32_16x16x32_f16(a0, b1, acc[0][1], 0, 0, 0);
            acc[1][0] = __builtin_amdgcn_mfma_f32_16x16x32_f16(a1, b0, acc[1][0], 0, 0, 0);
            acc[1][1] = __builtin_amdgcn_mfma_f32_16x16x32_f16(a1, b1, acc[1][1], 0, 0, 0);
        }
        __syncthreads();
    }

    // K-split reduction through LDS (spills past As into Bs; both dead here)
    float* red = (float*)As;
    const int rbase = (sq * 64 + lane) * 20;
    if (g == 1) {
#pragma unroll
        for (int fm = 0; fm < 2; ++fm)
#pragma unroll
            for (int fn = 0; fn < 2; ++fn)
                *(f32x4*)&red[rbase + (fm * 2 + fn) * 4] = acc[fm][fn];
    }
    __syncthreads();
    if (g == 0) {
#pragma unroll
        for (int fm = 0; fm < 2; ++fm)
#pragma unroll
            for (int fn = 0; fn < 2; ++fn)
                acc[fm][fn] += *(const f32x4*)&red[rbase + (fm * 2 + fn) * 4];

#pragma unroll
        for (int fm = 0; fm < 2; ++fm) {
#pragma unroll
            for (int fn = 0; fn < 2; ++fn) {
                const int row = m0 + wm * 32 + fm * 16 + (lane >> 4) * 4;
                const int col = n0 + wn * 32 + fn * 16 + (lane & 15);
                if constexpr (OEPI) {
#pragma unroll
                    for (int i = 0; i < 4; ++i) {
                        float v = tanh_(acc[fm][fn][i] + bo[col]);
                        outp[(size_t)(row + i) * (SS * NOUT) + (size_t)so * NOUT + col] = v;
                    }
                } else {
#pragma unroll
                    for (int i = 0; i < 4; ++i)
                        C[(size_t)(row + i) * ldc + col] = acc[fm][fn][i];
                }
            }
        }
        if constexpr (!OEPI) {
#pragma unroll
            for (int fn = 0; fn < 2; ++fn) {
                float s1 = 0.f, s2 = 0.f;
#pragma unroll
                for (int fm = 0; fm < 2; ++fm)
#pragma unroll
                    for (int i = 0; i < 4; ++i) { float v = acc[fm][fn][i]; s1 += v; s2 += v * v; }
                s1 += __shfl_xor(s1, 16, 64); s1 += __shfl_xor(s1, 32, 64);
                s2 += __shfl_xor(s2, 16, 64); s2 += __shfl_xor(s2, 32, 64);
                if (lane < 16) {
                    const int col = n0 + wn * 32 + fn * 16 + lane;
                    atomicAdd(&ssum[col], s1);
                    atomicAdd(&ssq[col], s2);
                }
            }
        }
    }
}

// ---------------- phase 1: ur-GEMM (256 jobs) + o(s-1)-GEMM (16 jobs), one launch ----------------
__global__ __launch_bounds__(512, 4)
void k_uro(const f16* __restrict__ comb, const f16* __restrict__ Wur, const f16* __restrict__ Wo16,
           float* __restrict__ pre_ur,
           float* __restrict__ ssum, float* __restrict__ ssq,
           const float* __restrict__ b_o, float* __restrict__ outp, int s)
{
    __shared__ __align__(16) f16 smem[2][2][64][72];
    const int b = blockIdx.x;
    if (b < 16) {                       // o(s-1): reads comb h-region = h_new(s-1)
        if (s == 0) return;
        const int m0 = (b >> 1) * 64, n0 = (b & 1) * 64;
        gemm_job<DH, true>(comb + NIN, DC, Wo16, nullptr, 0, nullptr, nullptr,
                           b_o, outp, s - 1, m0, n0, smem[0], smem[1]);
    } else {
        const int j = b - 16;
        const int m0 = (j >> 5) * 64, n0 = (j & 31) * 64;
        gemm_job<DC, false>(comb, DC, Wur, pre_ur, 2048, ssum, ssq,
                            nullptr, nullptr, 0, m0, n0, smem[0], smem[1]);
    }
}

// ---------------- phase 3: c-GEMM (128 jobs) ----------------
__global__ __launch_bounds__(512, 4)
void k_c8(const f16* __restrict__ comb, const f16* __restrict__ Wh16,
          float* __restrict__ pre_c, float* __restrict__ ssum, float* __restrict__ ssq)
{
    __shared__ __align__(16) f16 smem[2][2][64][72];
    const int b = blockIdx.x;
    const int m0 = (b >> 4) * 64, n0 = (b & 15) * 64;
    gemm_job<DC, false>(comb, DC, Wh16, pre_c, 1024, ssum, ssq,
                        nullptr, nullptr, 0, m0, n0, smem[0], smem[1]);
}

// ---------------- final o for s = 255 ----------------
__global__ __launch_bounds__(512, 4)
void k_o16(const f16* __restrict__ comb, const f16* __restrict__ Wo16,
           const float* __restrict__ b_o, float* __restrict__ outp)
{
    __shared__ __align__(16) f16 smem[2][2][64][72];
    const int b = blockIdx.x;
    const int m0 = (b >> 1) * 64, n0 = (b & 1) * 64;
    gemm_job<DH, true>(comb + NIN, DC, Wo16, nullptr, 0, nullptr, nullptr,
                       b_o, outp, SS - 1, m0, n0, smem[0], smem[1]);
}

// ---------------- gate kernel: r = sigmoid(BN(pre_r)); comb_h <- fp16(r*h) ----------------
__global__ __launch_bounds__(256)
void k_gate(const float* __restrict__ pre_ur, const float* __restrict__ h32,
            f16* __restrict__ comb,
            const float* __restrict__ ssum_ur, const float* __restrict__ ssq_ur,
            const float* __restrict__ g_r, const float* __restrict__ be_r)
{
    const int idx = blockIdx.x * 256 + threadIdx.x;
    const int m = idx >> 8, j4 = (idx & 255) << 2;
    float4 prv = *(const float4*)(pre_ur + (size_t)m * 2048 + 1024 + j4);
    float4 hv  = *(const float4*)(h32 + (size_t)m * 1024 + j4);
    float p[4] = {prv.x, prv.y, prv.z, prv.w};
    float h[4] = {hv.x, hv.y, hv.z, hv.w};
    f16x4 o;
#pragma unroll
    for (int t = 0; t < 4; ++t) {
        const int col = 1024 + j4 + t;
        float mu  = ssum_ur[col] * (1.0f / 512.0f);
        float var = fmaxf(ssq_ur[col] * (1.0f / 512.0f) - mu * mu, 0.f);
        float r   = sigmoid_(g_r[j4 + t] * ((p[t] - mu) * rsqrtf(var + EPSV)) + be_r[j4 + t]);
        o[t] = (f16)(r * h[t]);
    }
    *(f16x4*)(comb + (size_t)m * DC + NIN + j4) = o;
}

// ---------------- update kernel: u, c, h_new; prep next step ----------------
__global__ __launch_bounds__(256)
void k_upd(const float* __restrict__ pre_ur, const float* __restrict__ pre_c,
           float* __restrict__ h32, f16* __restrict__ comb,
           const float* __restrict__ ssum_ur, const float* __restrict__ ssq_ur,
           const float* __restrict__ ssum_c, const float* __restrict__ ssq_c,
           float* __restrict__ zsum_ur, float* __restrict__ zsq_ur,
           float* __restrict__ zsum_c, float* __restrict__ zsq_c,
           const float* __restrict__ X,
           const float* __restrict__ g_u, const float* __restrict__ be_u,
           const float* __restrict__ g_h, const float* __restrict__ be_h,
           int s)
{
    const int idx = blockIdx.x * 256 + threadIdx.x;
    const int m = idx >> 8, j4 = (idx & 255) << 2;
    float4 puv = *(const float4*)(pre_ur + (size_t)m * 2048 + j4);
    float4 pcv = *(const float4*)(pre_c + (size_t)m * 1024 + j4);
    float4 hv  = *(const float4*)(h32 + (size_t)m * 1024 + j4);
    float pu[4] = {puv.x, puv.y, puv.z, puv.w};
    float pc[4] = {pcv.x, pcv.y, pcv.z, pcv.w};
    float h[4]  = {hv.x, hv.y, hv.z, hv.w};
    float hn[4];
    f16x4 o;
#pragma unroll
    for (int t = 0; t < 4; ++t) {
        const int col = j4 + t;
        float mu_u  = ssum_ur[col] * (1.0f / 512.0f);
        float var_u = fmaxf(ssq_ur[col] * (1.0f / 512.0f) - mu_u * mu_u, 0.f);
        float u = sigmoid_(g_u[col] * ((pu[t] - mu_u) * rsqrtf(var_u + EPSV)) + be_u[col]);
        float mu_c  = ssum_c[col] * (1.0f / 512.0f);
        float var_c = fmaxf(ssq_c[col] * (1.0f / 512.0f) - mu_c * mu_c, 0.f);
        float c = tanh_(g_h[col] * ((pc[t] - mu_c) * rsqrtf(var_c + EPSV)) + be_h[col]);
        float hnew = (1.f - u) * c + u * h[t];
        hn[t] = hnew; o[t] = (f16)hnew;
    }
    *(float4*)(h32 + (size_t)m * 1024 + j4) = make_float4(hn[0], hn[1], hn[2], hn[3]);
    *(f16x4*)(comb + (size_t)m * DC + NIN + j4) = o;
    if (j4 < NIN && s + 1 < SS) {
        float4 xv = *(const float4*)(X + (size_t)m * SS * NIN + (size_t)(s + 1) * NIN + j4);
        f16x4 xo; xo[0] = (f16)xv.x; xo[1] = (f16)xv.y; xo[2] = (f16)xv.z; xo[3] = (f16)xv.w;
        *(f16x4*)(comb + (size_t)m * DC + j4) = xo;
    }
    if (idx < 2048) { zsum_ur[idx] = 0.f; zsq_ur[idx] = 0.f; }
    if (idx < 1024) { zsum_c[idx] = 0.f; zsq_c[idx] = 0.f; }
}

// ---------------- host launch ----------------
extern "C" void kernel_launch(void* const* d_in, const int* in_sizes, int n_in,
                              void* d_out, int out_size, void* d_ws, size_t ws_size,
                              hipStream_t stream)
{
    const float* X    = (const float*)d_in[0];
    const float* W_u  = (const float*)d_in[1];
    const float* W_r  = (const float*)d_in[3];
    const float* W_h  = (const float*)d_in[5];
    const float* W_o  = (const float*)d_in[7];
    const float* b_o  = (const float*)d_in[8];
    const float* g_u  = (const float*)d_in[9];
    const float* be_u = (const float*)d_in[10];
    const float* g_r  = (const float*)d_in[11];
    const float* be_r = (const float*)d_in[12];
    const float* g_h  = (const float*)d_in[13];
    const float* be_h = (const float*)d_in[14];
    float* out = (float*)d_out;

    char* p = (char*)d_ws;
    auto alloc = [&](size_t bytes) { char* r = p; p += (bytes + 255) & ~(size_t)255; return r; };
    f16*   comb    = (f16*)alloc((size_t)BB * DC * 2);
    f16*   Wur     = (f16*)alloc((size_t)2048 * DC * 2);
    f16*   Wh16    = (f16*)alloc((size_t)DH * DC * 2);
    f16*   Wo16    = (f16*)alloc((size_t)NOUT * DH * 2);
    float* pre_ur  = (float*)alloc((size_t)BB * 2048 * 4);
    float* pre_c   = (float*)alloc((size_t)BB * DH * 4);
    float* h32     = (float*)alloc((size_t)BB * DH * 4);
    float* ssum_ur = (float*)alloc(2 * 2048 * 4);
    float* ssq_ur  = (float*)alloc(2 * 2048 * 4);
    float* ssum_c  = (float*)alloc(2 * 1024 * 4);
    float* ssq_c   = (float*)alloc(2 * 1024 * 4);

    k_convert<<<1024, 256, 0, stream>>>(W_u, W_r, W_h, W_o, Wur, Wh16, Wo16);
    k_init<<<1024, 256, 0, stream>>>(X, comb, h32, ssum_ur, ssq_ur, ssum_c, ssq_c);

    for (int s = 0; s < SS; ++s) {
        const int par = s & 1, nxt = 1 - par;
        // phase 1: pre_ur = comb @ Wur^T (+stats)  ||  o(s-1) = tanh(h(s) @ Wo^T + b_o)
        k_uro<<<272, 512, 0, stream>>>(comb, Wur, Wo16, pre_ur,
                                       ssum_ur + par * 2048, ssq_ur + par * 2048,
                                       b_o, out, s);
        // phase 2: r = sigmoid(BN(pre_r)); comb_h <- r*h
        k_gate<<<512, 256, 0, stream>>>(pre_ur, h32, comb,
            ssum_ur + par * 2048, ssq_ur + par * 2048, g_r, be_r);
        // phase 3: pre_c = comb2 @ Wh^T (+stats)
        k_c8<<<128, 512, 0, stream>>>(comb, Wh16, pre_c,
                                      ssum_c + par * 1024, ssq_c + par * 1024);
        // phase 4: u, c, h_new; prep next step; zero next-parity stats
        k_upd<<<512, 256, 0, stream>>>(pre_ur, pre_c, h32, comb,
            ssum_ur + par * 2048, ssq_ur + par * 2048,
            ssum_c + par * 1024, ssq_c + par * 1024,
            ssum_ur + nxt * 2048, ssq_ur + nxt * 2048,
            ssum_c + nxt * 1024, ssq_c + nxt * 1024,
            X, g_u, be_u, g_h, be_h, s);
    }
    // final o for s = 255 (comb h-region holds h_new(255))
    k_o16<<<16, 512, 0, stream>>>(comb, Wo16, b_o, out);
}